// Round 2
// 3239.393 us; speedup vs baseline: 1.0460x; 1.0460x over previous
//
#include <hip/hip_runtime.h>

// Teacher-forced GRU + additive attention decoder, MI355X. FLOAT32 I/O.
// Round 11 (bisect): R10's NSL=8/512-thread scaffolding, but every per-step
// dataflow form reverted to the R9-proven variant:
//  - shfl broadcast of h-slice (not LDS sc_hn)
//  - scalar u32-pair gate-dot loops (not float4 LDS reads)
//  - one-thread-per-e ctx partial (not paired/shfl form)
//  - direct per-step stash/out_attn stores (no LDS rings)
// If this passes, the R10 failure was in the micro-opts; if not, the NSL=8
// protocol core is at fault.
#define BB    32
#define TDEC  400
#define TENC  800
#define EDIM  256
#define GDIM  256
#define ADIM  128
#define IDIM  80
#define G3    768
#define NSL   8     // slices (blocks) per batch element
#define SLH   32    // GDIM/NSL h-elements per slice
#define SLT   100   // TENC/NSL encoder timesteps per slice
#define FSTR  16    // flag/sum stride in words (64B line each)
#define EPST  136   // encp LDS row stride (u16), 16B aligned
#define ETST  102   // enc_t LDS row stride (u16): 51 u32/row

typedef unsigned short u16;
typedef unsigned int u32;

__device__ __forceinline__ float b2f(u16 u) {
  union { u32 i; float f; } x; x.i = ((u32)u) << 16; return x.f;
}
__device__ __forceinline__ u16 f2b(float f) {
  union { float f; u32 u; } x; x.f = f;
  u32 u = x.u; u += 0x7fffu + ((u >> 16) & 1u);
  return (u16)(u >> 16);
}
__device__ __forceinline__ void ld8(const u16* p, float* w) {
  const uint4 q = *reinterpret_cast<const uint4*>(p);
  union { u32 i; float f; } c;
  c.i = q.x << 16;          w[0] = c.f;
  c.i = q.x & 0xffff0000u;  w[1] = c.f;
  c.i = q.y << 16;          w[2] = c.f;
  c.i = q.y & 0xffff0000u;  w[3] = c.f;
  c.i = q.z << 16;          w[4] = c.f;
  c.i = q.z & 0xffff0000u;  w[5] = c.f;
  c.i = q.w << 16;          w[6] = c.f;
  c.i = q.w & 0xffff0000u;  w[7] = c.f;
}
__device__ __forceinline__ void ldf8(const float* p, float* w) {
  const float4 a = *reinterpret_cast<const float4*>(p);
  const float4 b = *reinterpret_cast<const float4*>(p + 4);
  w[0] = a.x; w[1] = a.y; w[2] = a.z; w[3] = a.w;
  w[4] = b.x; w[5] = b.y; w[6] = b.z; w[7] = b.w;
}
__device__ __forceinline__ float fsigmoid(float x) {
  return __builtin_amdgcn_rcpf(1.f + __expf(-x));
}
__device__ __forceinline__ float ftanh(float x) {
  float e = __expf(2.f * x);
  return 1.f - 2.f * __builtin_amdgcn_rcpf(e + 1.f);
}
// Relaxed agent-scope ops: bypass L1/L2 to LLC, no cache invalidation.
__device__ __forceinline__ void ast(float* p, float v) {
  __hip_atomic_store(p, v, __ATOMIC_RELAXED, __HIP_MEMORY_SCOPE_AGENT);
}
__device__ __forceinline__ float ald(const float* p) {
  return __hip_atomic_load(p, __ATOMIC_RELAXED, __HIP_MEMORY_SCOPE_AGENT);
}
__device__ __forceinline__ void aadd(float* p, float v) {
  (void)__hip_atomic_fetch_add(p, v, __ATOMIC_RELAXED, __HIP_MEMORY_SCOPE_AGENT);
}

// ---------------- K1: gi_x[b][t][g] = x_t . W_ih[:, :80] + b_ih (bf16 out) -----
__global__ __launch_bounds__(256) void k_gix(
    const float* __restrict__ gt, const float* __restrict__ W_ih,
    const float* __restrict__ b_ih, u16* __restrict__ gi_x) {
  __shared__ float sc_x[8][IDIM];
  const int tid = threadIdx.x;
  const int b = blockIdx.x / 50;
  const int t0 = (blockIdx.x % 50) * 8;
  for (int idx = tid; idx < 8 * IDIM; idx += 256) {
    int row = idx / IDIM, col = idx % IDIM;
    sc_x[row][col] = gt[((size_t)b * TDEC + t0 + row) * IDIM + col];
  }
  __syncthreads();
  for (int kk = 0; kk < 3; ++kk) {
    const int g = tid + 256 * kk;
    const float* wrow = W_ih + (size_t)g * 336;
    float acc[8] = {0,0,0,0,0,0,0,0};
    #pragma unroll 2
    for (int k8 = 0; k8 < IDIM / 8; ++k8) {
      float w[8]; ldf8(wrow + (k8 << 3), w);
      #pragma unroll
      for (int tt = 0; tt < 8; ++tt) {
        const float* x = &sc_x[tt][k8 << 3];
        acc[tt] += w[0]*x[0] + w[1]*x[1] + w[2]*x[2] + w[3]*x[3]
                 + w[4]*x[4] + w[5]*x[5] + w[6]*x[6] + w[7]*x[7];
      }
    }
    const float bias = b_ih[g];
    #pragma unroll
    for (int tt = 0; tt < 8; ++tt)
      gi_x[((size_t)b * TDEC + t0 + tt) * G3 + g] = f2b(acc[tt] + bias);
  }
}

// ------- K2: enc_proj (bf16) + bf16 copy of enc_feat ---------------------------
__global__ __launch_bounds__(256) void k_encp(
    const float* __restrict__ enc_feat, const float* __restrict__ W_enc,
    u16* __restrict__ encp, u16* __restrict__ enc_bf) {
  __shared__ float sc_x[16][EDIM];
  const int tid = threadIdx.x;
  const int b = blockIdx.x / 50;
  const int te0 = (blockIdx.x % 50) * 16;
  for (int idx = tid; idx < 16 * EDIM; idx += 256) {
    int row = idx >> 8, col = idx & 255;
    sc_x[row][col] = enc_feat[((size_t)b * TENC + te0 + row) * EDIM + col];
  }
  __syncthreads();
  const int a = tid & 127;
  const int tg = tid >> 7;
  const float* wrow = W_enc + (size_t)a * EDIM;
  float acc[8] = {0,0,0,0,0,0,0,0};
  #pragma unroll 4
  for (int k8 = 0; k8 < EDIM / 8; ++k8) {
    float w[8]; ldf8(wrow + (k8 << 3), w);
    #pragma unroll
    for (int tt = 0; tt < 8; ++tt) {
      const float* x = &sc_x[tg * 8 + tt][k8 << 3];
      acc[tt] += w[0]*x[0] + w[1]*x[1] + w[2]*x[2] + w[3]*x[3]
               + w[4]*x[4] + w[5]*x[5] + w[6]*x[6] + w[7]*x[7];
    }
  }
  #pragma unroll
  for (int tt = 0; tt < 8; ++tt)
    encp[((size_t)b * TENC + te0 + tg * 8 + tt) * ADIM + a] = f2b(acc[tt]);
  for (int idx = tid; idx < 16 * EDIM; idx += 256)
    enc_bf[((size_t)b * TENC + te0) * EDIM + idx] = f2b(sc_x[idx >> 8][idx & 255]);
}

// ---------------- K3: persistent step loop (8 blocks x 512 thr per batch) ------
__global__ __launch_bounds__(512, 1) void k_decode(
    const float* __restrict__ W_ih, const float* __restrict__ W_hh,
    const float* __restrict__ b_hh, const float* __restrict__ W_dec,
    const float* __restrict__ b_attn, const float* __restrict__ v_attn,
    const u16* __restrict__ gi_x, const u16* __restrict__ encp,
    const u16* __restrict__ enc_bf, float* __restrict__ stash,
    float* __restrict__ Xh, float* __restrict__ Dacc,
    float* __restrict__ Xctxacc, float* __restrict__ Xsumacc,
    int* __restrict__ flagA, int* __restrict__ flagB,
    float* __restrict__ out_attn) {
  extern __shared__ __align__(16) u16 dynlds[];
  u16* encp_lds = dynlds;              // SLT*EPST = 13600 u16 = 27200 B
  u16* enc_t    = dynlds + SLT * EPST; // EDIM*ETST = 26112 u16 = 52224 B [e][te]

  __shared__ u32 sWdp[ADIM * 17];                    // 8704 B, W_dec[:,slice]
  __shared__ __align__(16) float sc_h[256];          // h(t)
  __shared__ float sc_ing[4][68];   // ctx quarters, stride 68 (conflict-free)
  __shared__ float sc_inh[4][68];   // h quarters
  __shared__ float sc_dec[ADIM];
  __shared__ float sc_g0[96];   // W_ihc.ctx + gi_x
  __shared__ float sc_g1[96];   // W_hh.h + b_hh (shadow-computed)
  __shared__ float sc_w[104];
  __shared__ float sc_v[ADIM];
  __shared__ float sc_ba[ADIM];
  __shared__ float sc_bhh[96];
  __shared__ float sc_gx[96];
  __shared__ float sc_xs[4];

  const int tid = threadIdx.x;
  const int b = blockIdx.x & 31;
  const int j = blockIdx.x >> 5;      // 0..7
  const int lane = tid & 63;
  const int bank = j & 3;             // 2 blocks per bank

  // ---- one-time: gate weights -> registers (quad-split rows, 96 rows) ----
  u32 wctx[32], whh[32];
  #pragma unroll
  for (int i = 0; i < 32; ++i) { wctx[i] = 0u; whh[i] = 0u; }
  if (tid < 384) {
    const int r = tid >> 2, q = tid & 3;
    const int grow = (r >> 5) * 256 + SLH * j + (r & 31);
    const float2* s1 = reinterpret_cast<const float2*>(
        W_ih + (size_t)grow * 336 + 80 + q * 64);
    const float2* s2 = reinterpret_cast<const float2*>(
        W_hh + (size_t)grow * 256 + q * 64);
    #pragma unroll
    for (int i = 0; i < 32; ++i) {
      const float2 v1 = s1[i], v2 = s2[i];
      wctx[i] = (u32)f2b(v1.x) | ((u32)f2b(v1.y) << 16);
      whh[i]  = (u32)f2b(v2.x) | ((u32)f2b(v2.y) << 16);
    }
  }
  // ---- one-time LDS preloads ----
  for (int idx = tid; idx < ADIM * 16; idx += 512) {  // W_dec[:, 32-col slice]
    const int a = idx >> 4, k2 = idx & 15;
    const float2 v = *reinterpret_cast<const float2*>(
        W_dec + (size_t)a * GDIM + SLH * j + 2 * k2);
    sWdp[a * 17 + k2] = (u32)f2b(v.x) | ((u32)f2b(v.y) << 16);
  }
  for (int idx = tid; idx < SLT * ADIM; idx += 512) {
    const int te = idx >> 7, a = idx & 127;
    encp_lds[te * EPST + a] = encp[((size_t)b * TENC + SLT * j + te) * ADIM + a];
  }
  for (int idx = tid; idx < SLT * EDIM; idx += 512) {
    const int te = idx >> 8, e = idx & 255;
    enc_t[e * ETST + te] = enc_bf[((size_t)b * TENC + SLT * j + te) * EDIM + e];
  }
  if (tid < ADIM) { sc_v[tid] = v_attn[tid]; sc_ba[tid] = b_attn[tid]; }
  if (tid < 96) {
    const int grow = (tid >> 5) * 256 + SLH * j + (tid & 31);
    const float bh = b_hh[grow];
    sc_bhh[tid] = bh;
    sc_g1[tid] = bh;                                   // gh(h=0) = b_hh
    sc_gx[tid] = b2f(gi_x[((size_t)b * TDEC + 0) * G3 + grow]);
  }
  if (tid < 256) {
    sc_h[tid] = 0.f;
    sc_ing[tid >> 6][tid & 63] = 0.f;
    sc_inh[tid >> 6][tid & 63] = 0.f;
  }
  __syncthreads();

  for (int t = 0; t < TDEC; ++t) {
    const int p = t & 1;
    // -------- G0: ctx-half gate dots (register weights, strided LDS) ---------
    if (tid < 384) {
      const float* act = &sc_ing[tid & 3][0];
      float acc = 0.f;
      #pragma unroll
      for (int i = 0; i < 32; ++i) {
        union { u32 u; float f; } lo, hi;
        lo.u = wctx[i] << 16; hi.u = wctx[i] & 0xffff0000u;
        acc += lo.f * act[2 * i] + hi.f * act[2 * i + 1];
      }
      acc += __shfl_xor(acc, 1);
      acc += __shfl_xor(acc, 2);
      if ((tid & 3) == 0) sc_g0[tid >> 2] = acc + sc_gx[tid >> 2];
    }
    __syncthreads();  // B1: sc_g0 ready (sc_g1 from prev step's shadow)
    // -------- wave0: pointwise h + publish h-slice + dec partial -------------
    if (tid < 64) {
      float hval = 0.f;
      if (lane < SLH) {
        const float gr = sc_g0[lane] + sc_g1[lane];
        const float gz = sc_g0[SLH + lane] + sc_g1[SLH + lane];
        const float rr = fsigmoid(gr);
        const float zz = fsigmoid(gz);
        const float nn = ftanh(sc_g0[2 * SLH + lane] + rr * sc_g1[2 * SLH + lane]);
        const float hp = sc_h[SLH * j + lane];
        hval = (1.f - zz) * nn + zz * hp;
        ast(&Xh[b * GDIM + SLH * j + lane], hval);
      }
      float hn[32];
      #pragma unroll
      for (int k = 0; k < 32; ++k) hn[k] = __shfl(hval, k);
      #pragma unroll
      for (int r2 = 0; r2 < 2; ++r2) {
        const int a = lane + 64 * r2;
        const u32* wp = &sWdp[a * 17];
        float acc = 0.f;
        #pragma unroll
        for (int k2 = 0; k2 < 16; ++k2) {
          const u32 w2 = wp[k2];
          union { u32 u; float f; } lo, hi;
          lo.u = w2 << 16; hi.u = w2 & 0xffff0000u;
          acc += lo.f * hn[2 * k2] + hi.f * hn[2 * k2 + 1];
        }
        aadd(&Dacc[((p * BB + b) * 4 + bank) * ADIM + a], acc);
      }
    }
    __syncthreads();  // B2: drains wave0 publishes
    if (tid == 0)
      __hip_atomic_store(&flagA[(b * NSL + j) * FSTR], t + 1, __ATOMIC_RELAXED,
                         __HIP_MEMORY_SCOPE_AGENT);
    if (tid < NSL) {
      const int* fp = &flagA[(b * NSL + tid) * FSTR];
      while (__hip_atomic_load(fp, __ATOMIC_RELAXED,
                               __HIP_MEMORY_SCOPE_AGENT) < t + 1)
        __builtin_amdgcn_s_sleep(1);
    }
    __syncthreads();  // B3: sync A done
    if (tid < 256) {
      const float hv = ald(&Xh[b * GDIM + tid]);        // full h(t)
      sc_h[tid] = hv;
      sc_inh[tid >> 6][tid & 63] = hv;
      if (j == 0) stash[((size_t)b * TDEC + t) * 512 + tid] = hv;
    }
    if (tid < ADIM) {
      float d = sc_ba[tid];
      #pragma unroll
      for (int k = 0; k < 4; ++k)
        d += ald(&Dacc[((p * BB + b) * 4 + k) * ADIM + tid]);
      sc_dec[tid] = d;
    }
    // parity resets for 1-p on waves 4-7 (off the critical wave)
    if (tid >= 256 && tid < 384) {         // Xctx: 4*256 words; 128/block
      const int w = j * 128 + (tid - 256);
      ast(&Xctxacc[(((1 - p) * BB + b) * 4 + (w >> 8)) * EDIM + (w & 255)], 0.f);
    } else if (tid >= 384 && tid < 448) {  // Dacc: 4*128 words; 64/block
      const int w = j * 64 + (tid - 384);
      ast(&Dacc[(((1 - p) * BB + b) * 4 + (w >> 7)) * ADIM + (w & 127)], 0.f);
    } else if (tid == 448 && j < 4) {
      ast(&Xsumacc[(((1 - p) * BB + b) * 4 + j) * FSTR], 0.f);
    }
    __syncthreads();  // B4: sc_dec + h in LDS
    // -------- scores from LDS encp (4-way k-split, 400 threads) --------------
    if (tid < 400) {
      const int te = tid >> 2, q4 = tid & 3;
      const u16* ep = &encp_lds[te * EPST + q4 * 32];
      const float* dp = sc_dec + q4 * 32;
      const float* vp = sc_v + q4 * 32;
      float s = 0.f;
      #pragma unroll
      for (int k8 = 0; k8 < 4; ++k8) {
        float w[8]; ld8(ep + (k8 << 3), w);
        #pragma unroll
        for (int i = 0; i < 8; ++i) {
          const int a = (k8 << 3) + i;
          s += ftanh(w[i] + dp[a]) * vp[a];
        }
      }
      s += __shfl_xor(s, 1);
      s += __shfl_xor(s, 2);
      if (q4 == 0) sc_w[te] = __expf(s);  // |s| <= ||v||_1 ~ 5: max-free safe
    } else if (tid >= 448) {  // wave7: prefetch gi_x(t+1)
      const int tn = (t + 1 < TDEC) ? t + 1 : t;
      const int gl = tid - 448;
      {
        const int grow = (gl >> 5) * 256 + SLH * j + (gl & 31);
        sc_gx[gl] = b2f(gi_x[((size_t)b * TDEC + tn) * G3 + grow]);
      }
      if (gl < 32) {
        const int g2 = gl + 64;
        const int grow = (g2 >> 5) * 256 + SLH * j + (g2 & 31);
        sc_gx[g2] = b2f(gi_x[((size_t)b * TDEC + tn) * G3 + grow]);
      }
    }
    __syncthreads();  // B5: sc_w ready
    // -------- publish sum + ctx partial (banked atomic accumulate) -----------
    if (tid < 64) {
      float v = (lane < 50) ? sc_w[lane] + sc_w[lane + 50] : 0.f;
      #pragma unroll
      for (int off = 1; off < 64; off <<= 1) v += __shfl_xor(v, off);
      if (lane == 0) aadd(&Xsumacc[((p * BB + b) * 4 + bank) * FSTR], v);
    }
    if (tid < 256) {
      const u32* et = reinterpret_cast<const u32*>(&enc_t[tid * ETST]);
      float pc = 0.f;
      #pragma unroll
      for (int k2 = 0; k2 < 50; ++k2) {
        const u32 w2 = et[k2];
        union { u32 u; float f; } lo, hi;
        lo.u = w2 << 16; hi.u = w2 & 0xffff0000u;
        pc += sc_w[2 * k2] * lo.f + sc_w[2 * k2 + 1] * hi.f;
      }
      aadd(&Xctxacc[((p * BB + b) * 4 + bank) * EDIM + tid], pc);
    }
    // -------- shadow: gh(t) while sum/ctx adds propagate ---------------------
    if (tid < 384) {
      const float* act = &sc_inh[tid & 3][0];
      float acc = 0.f;
      #pragma unroll
      for (int i = 0; i < 32; ++i) {
        union { u32 u; float f; } lo, hi;
        lo.u = whh[i] << 16; hi.u = whh[i] & 0xffff0000u;
        acc += lo.f * act[2 * i] + hi.f * act[2 * i + 1];
      }
      acc += __shfl_xor(acc, 1);
      acc += __shfl_xor(acc, 2);
      if ((tid & 3) == 0) sc_g1[tid >> 2] = acc + sc_bhh[tid >> 2];
    }
    __syncthreads();  // B6: drains each wave's own sum/ctx adds
    if (tid == 0)
      __hip_atomic_store(&flagB[(b * NSL + j) * FSTR], t + 1, __ATOMIC_RELAXED,
                         __HIP_MEMORY_SCOPE_AGENT);
    if (tid < NSL) {
      const int* fp = &flagB[(b * NSL + tid) * FSTR];
      while (__hip_atomic_load(fp, __ATOMIC_RELAXED,
                               __HIP_MEMORY_SCOPE_AGENT) < t + 1)
        __builtin_amdgcn_s_sleep(1);
      if (tid < 4) sc_xs[tid] = ald(&Xsumacc[((p * BB + b) * 4 + tid) * FSTR]);
    }
    __syncthreads();  // B7: sync B done, sc_xs ready
    // -------- epilogue (direct per-step stores, R9 form) ---------------------
    {
      const float S = sc_xs[0] + sc_xs[1] + sc_xs[2] + sc_xs[3];
      const float invS = __builtin_amdgcn_rcpf(S);
      if (tid < 256) {
        float c = 0.f;
        #pragma unroll
        for (int k = 0; k < 4; ++k)
          c += ald(&Xctxacc[((p * BB + b) * 4 + k) * EDIM + tid]);
        const float cv = c * invS;
        sc_ing[tid >> 6][tid & 63] = cv;  // ctx(t) for next-step gates
        if (j == 0) stash[((size_t)b * TDEC + t) * 512 + 256 + tid] = cv;
      }
      if (tid < SLT)
        out_attn[((size_t)b * TDEC + t) * TENC + SLT * j + tid] =
            sc_w[tid] * invS;
    }
    __syncthreads();  // B8
  }
}

// ---------------- K4: pred = log_softmax([h;ctx] . W_out^T + b_out) ------------
__global__ __launch_bounds__(256) void k_pred(
    const float* __restrict__ stash, const float* __restrict__ W_out,
    const float* __restrict__ b_out, float* __restrict__ out_pred) {
  __shared__ float sc_s[4][512];
  __shared__ float sc_lp[2][4][IDIM];
  __shared__ float sc_l[4][IDIM];
  __shared__ float sc_lse[4];
  const int tid = threadIdx.x;
  const int b = blockIdx.x / 100;
  const int t0 = (blockIdx.x % 100) * 4;
  for (int idx = tid; idx < 4 * 512; idx += 256)
    sc_s[idx >> 9][idx & 511] = stash[((size_t)b * TDEC + t0) * 512 + idx];
  __syncthreads();
  const int o = tid & 127, kh = tid >> 7;
  if (o < IDIM) {
    const float* wrow = W_out + (size_t)o * 512 + kh * 256;
    float acc[4] = {0,0,0,0};
    #pragma unroll 4
    for (int k8 = 0; k8 < 32; ++k8) {
      float w[8]; ldf8(wrow + (k8 << 3), w);
      #pragma unroll
      for (int tt = 0; tt < 4; ++tt) {
        const float* x = &sc_s[tt][kh * 256 + (k8 << 3)];
        acc[tt] += w[0]*x[0] + w[1]*x[1] + w[2]*x[2] + w[3]*x[3]
                 + w[4]*x[4] + w[5]*x[5] + w[6]*x[6] + w[7]*x[7];
      }
    }
    #pragma unroll
    for (int tt = 0; tt < 4; ++tt) sc_lp[kh][tt][o] = acc[tt];
  }
  __syncthreads();
  if (tid < IDIM) {
    const float bb = b_out[tid];
    #pragma unroll
    for (int tt = 0; tt < 4; ++tt)
      sc_l[tt][tid] = sc_lp[0][tt][tid] + sc_lp[1][tt][tid] + bb;
  }
  __syncthreads();
  {
    const int w = tid >> 6, lane = tid & 63;
    const float a0 = sc_l[w][lane];
    const float a1 = (lane < IDIM - 64) ? sc_l[w][lane + 64] : -1e30f;
    float m = fmaxf(a0, a1);
    #pragma unroll
    for (int off = 1; off < 64; off <<= 1) m = fmaxf(m, __shfl_xor(m, off));
    float e = __expf(a0 - m) + ((lane < IDIM - 64) ? __expf(a1 - m) : 0.f);
    #pragma unroll
    for (int off = 1; off < 64; off <<= 1) e += __shfl_xor(e, off);
    if (lane == 0) sc_lse[w] = m + __logf(e);
  }
  __syncthreads();
  for (int idx = tid; idx < 4 * IDIM; idx += 256) {
    const int tt = idx / IDIM, oo = idx % IDIM;
    out_pred[((size_t)b * TDEC + t0 + tt) * IDIM + oo] =
        sc_l[tt][oo] - sc_lse[tt];
  }
}

extern "C" void kernel_launch(void* const* d_in, const int* in_sizes, int n_in,
                              void* d_out, int out_size, void* d_ws, size_t ws_size,
                              hipStream_t stream) {
  const float* enc_feat = (const float*)d_in[0];
  const float* gt       = (const float*)d_in[1];
  const float* W_ih     = (const float*)d_in[2];
  const float* W_hh     = (const float*)d_in[3];
  const float* b_ih     = (const float*)d_in[4];
  const float* b_hh     = (const float*)d_in[5];
  const float* W_enc    = (const float*)d_in[6];
  const float* W_dec    = (const float*)d_in[7];
  const float* b_attn   = (const float*)d_in[8];
  const float* v_attn   = (const float*)d_in[9];
  const float* W_out    = (const float*)d_in[10];
  const float* b_out    = (const float*)d_in[11];
  float* out_pred = (float*)d_out;
  float* out_attn = out_pred + (size_t)BB * TDEC * IDIM;

  char* ws = (char*)d_ws;
  size_t off = 0;
  u16* gi_x   = (u16*)(ws + off);   off += (size_t)BB * TDEC * G3 * 2;
  u16* encp   = (u16*)(ws + off);   off += (size_t)BB * TENC * ADIM * 2;
  u16* enc_bf = (u16*)(ws + off);   off += (size_t)BB * TENC * EDIM * 2;
  float* stash= (float*)(ws + off); off += (size_t)BB * TDEC * 512 * 4;
  float* Xh   = (float*)(ws + off); off += (size_t)BB * GDIM * 4;
  // ---- zeroed region (one memset): flags + banked accumulators ----
  char* zbase = ws + off;
  int* flagA    = (int*)(ws + off);   off += (size_t)BB * NSL * FSTR * 4;
  int* flagB    = (int*)(ws + off);   off += (size_t)BB * NSL * FSTR * 4;
  float* Dacc   = (float*)(ws + off); off += (size_t)BB * 2 * 4 * ADIM * 4;
  float* Xctxacc= (float*)(ws + off); off += (size_t)BB * 2 * 4 * EDIM * 4;
  float* Xsumacc= (float*)(ws + off); off += (size_t)BB * 2 * 4 * FSTR * 4;
  const size_t zbytes = (size_t)(ws + off - zbase);

  // dynamic LDS for k_decode: encp slice + transposed enc slice
  const int DYNB = (SLT * EPST + EDIM * ETST) * 2;  // 79424 B
  static bool s_attr = false;
  if (!s_attr) {
    (void)hipFuncSetAttribute(reinterpret_cast<const void*>(k_decode),
                              hipFuncAttributeMaxDynamicSharedMemorySize, DYNB);
    s_attr = true;
  }

  hipMemsetAsync(zbase, 0, zbytes, stream);

  hipLaunchKernelGGL(k_gix, dim3(BB * 50), dim3(256), 0, stream,
                     gt, W_ih, b_ih, gi_x);
  hipLaunchKernelGGL(k_encp, dim3(BB * 50), dim3(256), 0, stream,
                     enc_feat, W_enc, encp, enc_bf);
  hipLaunchKernelGGL(k_decode, dim3(BB * NSL), dim3(512), DYNB, stream,
                     W_ih, W_hh, b_hh, W_dec, b_attn, v_attn,
                     gi_x, encp, enc_bf, stash, Xh, Dacc, Xctxacc, Xsumacc,
                     flagA, flagB, out_attn);
  hipLaunchKernelGGL(k_pred, dim3(BB * 100), dim3(256), 0, stream,
                     stash, W_out, b_out, out_pred);
}

// Round 4
// 2830.684 us; speedup vs baseline: 1.1970x; 1.1444x over previous
//
#include <hip/hip_runtime.h>

// Teacher-forced GRU + additive attention decoder, MI355X. FLOAT32 I/O.
// Round 13: epoch-tagged slot protocol ("data is the flag").
// R11 baseline (passing, 3.06ms k_decode): per step = 2 sync hops, each
// costing ~4 serial LLC round trips (add-drain, flag store, poll, data read).
// This round: every published value is an 8B packet {f32 val, u32 tag=t+1}
// stored with ONE atomic dwordx2 (single-transaction visibility). Readers
// poll slots directly until tag==t+1. Removes flags, atomic adds, drains and
// all parity resets (two-hop rendezvous makes overwrite-while-reading
// impossible -> no double buffering). Barriers 8 -> 5 per step.
// sc_h overwrite race closed by keeping own h-slice in register (hprev).
#define BB    32
#define TDEC  400
#define TENC  800
#define EDIM  256
#define GDIM  256
#define ADIM  128
#define IDIM  80
#define G3    768
#define NSL   8     // slices (blocks) per batch element
#define SLH   32    // GDIM/NSL h-elements per slice
#define SLT   100   // TENC/NSL encoder timesteps per slice
#define XCST  257   // XctxS per-block slot count (256 e + 1 sum)
#define EPST  136   // encp LDS row stride (u16), 16B aligned
#define ETST  102   // enc_t LDS row stride (u16): 51 u32/row

typedef unsigned short u16;
typedef unsigned int u32;
typedef unsigned long long u64;

__device__ __forceinline__ float b2f(u16 u) {
  union { u32 i; float f; } x; x.i = ((u32)u) << 16; return x.f;
}
__device__ __forceinline__ u16 f2b(float f) {
  union { float f; u32 u; } x; x.f = f;
  u32 u = x.u; u += 0x7fffu + ((u >> 16) & 1u);
  return (u16)(u >> 16);
}
__device__ __forceinline__ void ld8(const u16* p, float* w) {
  const uint4 q = *reinterpret_cast<const uint4*>(p);
  union { u32 i; float f; } c;
  c.i = q.x << 16;          w[0] = c.f;
  c.i = q.x & 0xffff0000u;  w[1] = c.f;
  c.i = q.y << 16;          w[2] = c.f;
  c.i = q.y & 0xffff0000u;  w[3] = c.f;
  c.i = q.z << 16;          w[4] = c.f;
  c.i = q.z & 0xffff0000u;  w[5] = c.f;
  c.i = q.w << 16;          w[6] = c.f;
  c.i = q.w & 0xffff0000u;  w[7] = c.f;
}
__device__ __forceinline__ void ldf8(const float* p, float* w) {
  const float4 a = *reinterpret_cast<const float4*>(p);
  const float4 b = *reinterpret_cast<const float4*>(p + 4);
  w[0] = a.x; w[1] = a.y; w[2] = a.z; w[3] = a.w;
  w[4] = b.x; w[5] = b.y; w[6] = b.z; w[7] = b.w;
}
__device__ __forceinline__ float fsigmoid(float x) {
  return __builtin_amdgcn_rcpf(1.f + __expf(-x));
}
__device__ __forceinline__ float ftanh(float x) {
  float e = __expf(2.f * x);
  return 1.f - 2.f * __builtin_amdgcn_rcpf(e + 1.f);
}
// ---- epoch-tagged 8B slots (agent scope, relaxed) ----
__device__ __forceinline__ void pst(float2* p, float v, u32 tag) {
  union { u64 u; u32 w[2]; } pk;
  pk.w[0] = __float_as_uint(v); pk.w[1] = tag;
  __hip_atomic_store((u64*)p, pk.u, __ATOMIC_RELAXED, __HIP_MEMORY_SCOPE_AGENT);
}
__device__ __forceinline__ u64 pld(const float2* p) {
  return __hip_atomic_load((const u64*)p, __ATOMIC_RELAXED,
                           __HIP_MEMORY_SCOPE_AGENT);
}
// poll one slot until tag matches, return value
__device__ __forceinline__ float poll1(const float2* p, u32 tag) {
  for (;;) {
    const u64 x = pld(p);
    if ((u32)(x >> 32) == tag) return __uint_as_float((u32)x);
    __builtin_amdgcn_s_sleep(1);
  }
}
// poll 8 strided slots until all tags match, return sum of values + init
__device__ __forceinline__ float gather8(const float2* base, int stride,
                                         u32 tag, float init) {
  u64 x[8];
  for (;;) {
    bool ok = true;
    #pragma unroll
    for (int k = 0; k < 8; ++k) x[k] = pld(base + (size_t)k * stride);
    #pragma unroll
    for (int k = 0; k < 8; ++k) ok &= ((u32)(x[k] >> 32) == tag);
    if (ok) break;
    __builtin_amdgcn_s_sleep(1);
  }
  float s = init;
  #pragma unroll
  for (int k = 0; k < 8; ++k) s += __uint_as_float((u32)x[k]);
  return s;
}

// ---------------- K1: gi_x[b][t][g] = x_t . W_ih[:, :80] + b_ih (bf16 out) -----
__global__ __launch_bounds__(256) void k_gix(
    const float* __restrict__ gt, const float* __restrict__ W_ih,
    const float* __restrict__ b_ih, u16* __restrict__ gi_x) {
  __shared__ float sc_x[8][IDIM];
  const int tid = threadIdx.x;
  const int b = blockIdx.x / 50;
  const int t0 = (blockIdx.x % 50) * 8;
  for (int idx = tid; idx < 8 * IDIM; idx += 256) {
    int row = idx / IDIM, col = idx % IDIM;
    sc_x[row][col] = gt[((size_t)b * TDEC + t0 + row) * IDIM + col];
  }
  __syncthreads();
  for (int kk = 0; kk < 3; ++kk) {
    const int g = tid + 256 * kk;
    const float* wrow = W_ih + (size_t)g * 336;
    float acc[8] = {0,0,0,0,0,0,0,0};
    #pragma unroll 2
    for (int k8 = 0; k8 < IDIM / 8; ++k8) {
      float w[8]; ldf8(wrow + (k8 << 3), w);
      #pragma unroll
      for (int tt = 0; tt < 8; ++tt) {
        const float* x = &sc_x[tt][k8 << 3];
        acc[tt] += w[0]*x[0] + w[1]*x[1] + w[2]*x[2] + w[3]*x[3]
                 + w[4]*x[4] + w[5]*x[5] + w[6]*x[6] + w[7]*x[7];
      }
    }
    const float bias = b_ih[g];
    #pragma unroll
    for (int tt = 0; tt < 8; ++tt)
      gi_x[((size_t)b * TDEC + t0 + tt) * G3 + g] = f2b(acc[tt] + bias);
  }
}

// ------- K2: enc_proj (bf16) + bf16 copy of enc_feat ---------------------------
__global__ __launch_bounds__(256) void k_encp(
    const float* __restrict__ enc_feat, const float* __restrict__ W_enc,
    u16* __restrict__ encp, u16* __restrict__ enc_bf) {
  __shared__ float sc_x[16][EDIM];
  const int tid = threadIdx.x;
  const int b = blockIdx.x / 50;
  const int te0 = (blockIdx.x % 50) * 16;
  for (int idx = tid; idx < 16 * EDIM; idx += 256) {
    int row = idx >> 8, col = idx & 255;
    sc_x[row][col] = enc_feat[((size_t)b * TENC + te0 + row) * EDIM + col];
  }
  __syncthreads();
  const int a = tid & 127;
  const int tg = tid >> 7;
  const float* wrow = W_enc + (size_t)a * EDIM;
  float acc[8] = {0,0,0,0,0,0,0,0};
  #pragma unroll 4
  for (int k8 = 0; k8 < EDIM / 8; ++k8) {
    float w[8]; ldf8(wrow + (k8 << 3), w);
    #pragma unroll
    for (int tt = 0; tt < 8; ++tt) {
      const float* x = &sc_x[tg * 8 + tt][k8 << 3];
      acc[tt] += w[0]*x[0] + w[1]*x[1] + w[2]*x[2] + w[3]*x[3]
               + w[4]*x[4] + w[5]*x[5] + w[6]*x[6] + w[7]*x[7];
    }
  }
  #pragma unroll
  for (int tt = 0; tt < 8; ++tt)
    encp[((size_t)b * TENC + te0 + tg * 8 + tt) * ADIM + a] = f2b(acc[tt]);
  for (int idx = tid; idx < 16 * EDIM; idx += 256)
    enc_bf[((size_t)b * TENC + te0) * EDIM + idx] = f2b(sc_x[idx >> 8][idx & 255]);
}

// ---------------- K3: persistent step loop (8 blocks x 512 thr per batch) ------
__global__ __launch_bounds__(512, 1) void k_decode(
    const float* __restrict__ W_ih, const float* __restrict__ W_hh,
    const float* __restrict__ b_hh, const float* __restrict__ W_dec,
    const float* __restrict__ b_attn, const float* __restrict__ v_attn,
    const u16* __restrict__ gi_x, const u16* __restrict__ encp,
    const u16* __restrict__ enc_bf, float* __restrict__ stash,
    float2* __restrict__ XhS, float2* __restrict__ DaccS,
    float2* __restrict__ XctxS, float* __restrict__ out_attn) {
  extern __shared__ __align__(16) u16 dynlds[];
  u16* encp_lds = dynlds;              // SLT*EPST = 13600 u16 = 27200 B
  u16* enc_t    = dynlds + SLT * EPST; // EDIM*ETST = 26112 u16 = 52224 B [e][te]

  __shared__ u32 sWdp[ADIM * 17];                    // 8704 B, W_dec[:,slice]
  __shared__ __align__(16) float sc_h[256];          // h(t)
  __shared__ float sc_ing[4][68];   // ctx quarters, stride 68 (conflict-free)
  __shared__ float sc_inh[4][68];   // h quarters
  __shared__ float sc_dec[ADIM];
  __shared__ float sc_g0[96];   // W_ihc.ctx + gi_x
  __shared__ float sc_g1[96];   // W_hh.h + b_hh (shadow-computed)
  __shared__ float sc_w[104];
  __shared__ float sc_v[ADIM];
  __shared__ float sc_ba[ADIM];
  __shared__ float sc_bhh[96];
  __shared__ float sc_gx[96];
  __shared__ float sc_S;

  const int tid = threadIdx.x;
  const int b = blockIdx.x & 31;
  const int j = blockIdx.x >> 5;      // 0..7
  const int lane = tid & 63;

  // ---- one-time: gate weights -> registers (quad-split rows, 96 rows) ----
  u32 wctx[32], whh[32];
  #pragma unroll
  for (int i = 0; i < 32; ++i) { wctx[i] = 0u; whh[i] = 0u; }
  if (tid < 384) {
    const int r = tid >> 2, q = tid & 3;
    const int grow = (r >> 5) * 256 + SLH * j + (r & 31);
    const float2* s1 = reinterpret_cast<const float2*>(
        W_ih + (size_t)grow * 336 + 80 + q * 64);
    const float2* s2 = reinterpret_cast<const float2*>(
        W_hh + (size_t)grow * 256 + q * 64);
    #pragma unroll
    for (int i = 0; i < 32; ++i) {
      const float2 v1 = s1[i], v2 = s2[i];
      wctx[i] = (u32)f2b(v1.x) | ((u32)f2b(v1.y) << 16);
      whh[i]  = (u32)f2b(v2.x) | ((u32)f2b(v2.y) << 16);
    }
  }
  // ---- one-time LDS preloads ----
  for (int idx = tid; idx < ADIM * 16; idx += 512) {  // W_dec[:, 32-col slice]
    const int a = idx >> 4, k2 = idx & 15;
    const float2 v = *reinterpret_cast<const float2*>(
        W_dec + (size_t)a * GDIM + SLH * j + 2 * k2);
    sWdp[a * 17 + k2] = (u32)f2b(v.x) | ((u32)f2b(v.y) << 16);
  }
  for (int idx = tid; idx < SLT * ADIM; idx += 512) {
    const int te = idx >> 7, a = idx & 127;
    encp_lds[te * EPST + a] = encp[((size_t)b * TENC + SLT * j + te) * ADIM + a];
  }
  for (int idx = tid; idx < SLT * EDIM; idx += 512) {
    const int te = idx >> 8, e = idx & 255;
    enc_t[e * ETST + te] = enc_bf[((size_t)b * TENC + SLT * j + te) * EDIM + e];
  }
  if (tid < ADIM) { sc_v[tid] = v_attn[tid]; sc_ba[tid] = b_attn[tid]; }
  if (tid < 96) {
    const int grow = (tid >> 5) * 256 + SLH * j + (tid & 31);
    const float bh = b_hh[grow];
    sc_bhh[tid] = bh;
    sc_g1[tid] = bh;                                   // gh(h=0) = b_hh
    sc_gx[tid] = b2f(gi_x[((size_t)b * TDEC + 0) * G3 + grow]);
  }
  if (tid < 256) {
    sc_h[tid] = 0.f;
    sc_ing[tid >> 6][tid & 63] = 0.f;
    sc_inh[tid >> 6][tid & 63] = 0.f;
  }
  float hprev = 0.f;   // own h-slice element (wave0, lane<SLH), reg-resident
  __syncthreads();

  for (int t = 0; t < TDEC; ++t) {
    const u32 tag = (u32)(t + 1);
    // -------- G0: ctx-half gate dots (register weights, strided LDS) ---------
    if (tid < 384) {
      const float* act = &sc_ing[tid & 3][0];
      float acc = 0.f;
      #pragma unroll
      for (int i = 0; i < 32; ++i) {
        union { u32 u; float f; } lo, hi;
        lo.u = wctx[i] << 16; hi.u = wctx[i] & 0xffff0000u;
        acc += lo.f * act[2 * i] + hi.f * act[2 * i + 1];
      }
      acc += __shfl_xor(acc, 1);
      acc += __shfl_xor(acc, 2);
      if ((tid & 3) == 0) sc_g0[tid >> 2] = acc + sc_gx[tid >> 2];
    }
    __syncthreads();  // B1: sc_g0 ready (sc_g1 from prev step's shadow)
    // -------- hop A: wave0 publishes h-slice + dec partial; all gather -------
    if (tid < 64) {
      float hval = 0.f;
      if (lane < SLH) {
        const float gr = sc_g0[lane] + sc_g1[lane];
        const float gz = sc_g0[SLH + lane] + sc_g1[SLH + lane];
        const float rr = fsigmoid(gr);
        const float zz = fsigmoid(gz);
        const float nn = ftanh(sc_g0[2 * SLH + lane] + rr * sc_g1[2 * SLH + lane]);
        hval = (1.f - zz) * nn + zz * hprev;
        hprev = hval;
        pst(&XhS[b * GDIM + SLH * j + lane], hval, tag);  // publish h early
      }
      float hn[32];
      #pragma unroll
      for (int k = 0; k < 32; ++k) hn[k] = __shfl(hval, k);
      #pragma unroll
      for (int r2 = 0; r2 < 2; ++r2) {
        const int a = lane + 64 * r2;
        const u32* wp = &sWdp[a * 17];
        float acc = 0.f;
        #pragma unroll
        for (int k2 = 0; k2 < 16; ++k2) {
          const u32 w2 = wp[k2];
          union { u32 u; float f; } lo, hi;
          lo.u = w2 << 16; hi.u = w2 & 0xffff0000u;
          acc += lo.f * hn[2 * k2] + hi.f * hn[2 * k2 + 1];
        }
        pst(&DaccS[(b * NSL + j) * ADIM + a], acc, tag);
      }
    }
    // gather (no flags, no drain: poll the tagged slots directly)
    if (tid < 128) {
      sc_dec[tid] = gather8(&DaccS[b * NSL * ADIM + tid], ADIM, tag, sc_ba[tid]);
    } else if (tid < 384) {
      const int g = tid - 128;
      const float hv = poll1(&XhS[b * GDIM + g], tag);
      sc_h[g] = hv;
      sc_inh[g >> 6][g & 63] = hv;
    }
    __syncthreads();  // B4: sc_dec + full h in LDS
    // -------- scores (tid<400) | stash-h (400-447, j==0) | prefetch (448+) ---
    if (tid < 400) {
      const int te = tid >> 2, q4 = tid & 3;
      const u16* ep = &encp_lds[te * EPST + q4 * 32];
      const float* dp = sc_dec + q4 * 32;
      const float* vp = sc_v + q4 * 32;
      float s = 0.f;
      #pragma unroll
      for (int k8 = 0; k8 < 4; ++k8) {
        float w[8]; ld8(ep + (k8 << 3), w);
        #pragma unroll
        for (int i = 0; i < 8; ++i) {
          const int a = (k8 << 3) + i;
          s += ftanh(w[i] + dp[a]) * vp[a];
        }
      }
      s += __shfl_xor(s, 1);
      s += __shfl_xor(s, 2);
      if (q4 == 0) sc_w[te] = __expf(s);  // |s| <= ||v||_1 ~ 5: max-free safe
    } else if (tid < 448) {
      if (j == 0) {
        for (int g = tid - 400; g < 256; g += 48)
          stash[((size_t)b * TDEC + t) * 512 + g] = sc_h[g];
      }
    } else {  // wave7: prefetch gi_x(t+1)
      const int tn = (t + 1 < TDEC) ? t + 1 : t;
      const int gl = tid - 448;
      {
        const int grow = (gl >> 5) * 256 + SLH * j + (gl & 31);
        sc_gx[gl] = b2f(gi_x[((size_t)b * TDEC + tn) * G3 + grow]);
      }
      if (gl < 32) {
        const int g2 = gl + 64;
        const int grow = (g2 >> 5) * 256 + SLH * j + (g2 & 31);
        sc_gx[g2] = b2f(gi_x[((size_t)b * TDEC + tn) * G3 + grow]);
      }
    }
    __syncthreads();  // B5: sc_w ready
    // -------- hop B: publish ctx partials + wsum; shadow gh; gather ----------
    if (tid < 256) {
      const u32* et = reinterpret_cast<const u32*>(&enc_t[tid * ETST]);
      float pc = 0.f;
      #pragma unroll
      for (int k2 = 0; k2 < 50; ++k2) {
        const u32 w2 = et[k2];
        union { u32 u; float f; } lo, hi;
        lo.u = w2 << 16; hi.u = w2 & 0xffff0000u;
        pc += sc_w[2 * k2] * lo.f + sc_w[2 * k2 + 1] * hi.f;
      }
      pst(&XctxS[(b * NSL + j) * XCST + tid], pc, tag);
    }
    if (tid < 64) {
      float v = (lane < 50) ? sc_w[lane] + sc_w[lane + 50] : 0.f;
      #pragma unroll
      for (int off = 1; off < 64; off <<= 1) v += __shfl_xor(v, off);
      if (lane == 0) pst(&XctxS[(b * NSL + j) * XCST + 256], v, tag);
    }
    // shadow: gh(t) = W_hh.h(t) + b_hh, overlaps slot propagation
    if (tid < 384) {
      const float* act = &sc_inh[tid & 3][0];
      float acc = 0.f;
      #pragma unroll
      for (int i = 0; i < 32; ++i) {
        union { u32 u; float f; } lo, hi;
        lo.u = whh[i] << 16; hi.u = whh[i] & 0xffff0000u;
        acc += lo.f * act[2 * i] + hi.f * act[2 * i + 1];
      }
      acc += __shfl_xor(acc, 1);
      acc += __shfl_xor(acc, 2);
      if ((tid & 3) == 0) sc_g1[tid >> 2] = acc + sc_bhh[tid >> 2];
    }
    float csum = 0.f;
    if (tid < 256) {
      csum = gather8(&XctxS[b * NSL * XCST + tid], XCST, tag, 0.f);
    } else if (tid == 256) {
      sc_S = gather8(&XctxS[b * NSL * XCST + 256], XCST, tag, 0.f);
    }
    __syncthreads();  // B7: csum in regs, sc_S ready
    // -------- epilogue -------------------------------------------------------
    {
      const float invS = __builtin_amdgcn_rcpf(sc_S);
      if (tid < 256) {
        const float cv = csum * invS;
        sc_ing[tid >> 6][tid & 63] = cv;  // ctx(t) for next-step gates
        if (j == 0) stash[((size_t)b * TDEC + t) * 512 + 256 + tid] = cv;
      }
      if (tid < SLT)
        out_attn[((size_t)b * TDEC + t) * TENC + SLT * j + tid] =
            sc_w[tid] * invS;
    }
    __syncthreads();  // B8
  }
}

// ---------------- K4: pred = log_softmax([h;ctx] . W_out^T + b_out) ------------
__global__ __launch_bounds__(256) void k_pred(
    const float* __restrict__ stash, const float* __restrict__ W_out,
    const float* __restrict__ b_out, float* __restrict__ out_pred) {
  __shared__ float sc_s[4][512];
  __shared__ float sc_lp[2][4][IDIM];
  __shared__ float sc_l[4][IDIM];
  __shared__ float sc_lse[4];
  const int tid = threadIdx.x;
  const int b = blockIdx.x / 100;
  const int t0 = (blockIdx.x % 100) * 4;
  for (int idx = tid; idx < 4 * 512; idx += 256)
    sc_s[idx >> 9][idx & 511] = stash[((size_t)b * TDEC + t0) * 512 + idx];
  __syncthreads();
  const int o = tid & 127, kh = tid >> 7;
  if (o < IDIM) {
    const float* wrow = W_out + (size_t)o * 512 + kh * 256;
    float acc[4] = {0,0,0,0};
    #pragma unroll 4
    for (int k8 = 0; k8 < 32; ++k8) {
      float w[8]; ldf8(wrow + (k8 << 3), w);
      #pragma unroll
      for (int tt = 0; tt < 4; ++tt) {
        const float* x = &sc_s[tt][kh * 256 + (k8 << 3)];
        acc[tt] += w[0]*x[0] + w[1]*x[1] + w[2]*x[2] + w[3]*x[3]
                 + w[4]*x[4] + w[5]*x[5] + w[6]*x[6] + w[7]*x[7];
      }
    }
    #pragma unroll
    for (int tt = 0; tt < 4; ++tt) sc_lp[kh][tt][o] = acc[tt];
  }
  __syncthreads();
  if (tid < IDIM) {
    const float bb = b_out[tid];
    #pragma unroll
    for (int tt = 0; tt < 4; ++tt)
      sc_l[tt][tid] = sc_lp[0][tt][tid] + sc_lp[1][tt][tid] + bb;
  }
  __syncthreads();
  {
    const int w = tid >> 6, lane = tid & 63;
    const float a0 = sc_l[w][lane];
    const float a1 = (lane < IDIM - 64) ? sc_l[w][lane + 64] : -1e30f;
    float m = fmaxf(a0, a1);
    #pragma unroll
    for (int off = 1; off < 64; off <<= 1) m = fmaxf(m, __shfl_xor(m, off));
    float e = __expf(a0 - m) + ((lane < IDIM - 64) ? __expf(a1 - m) : 0.f);
    #pragma unroll
    for (int off = 1; off < 64; off <<= 1) e += __shfl_xor(e, off);
    if (lane == 0) sc_lse[w] = m + __logf(e);
  }
  __syncthreads();
  for (int idx = tid; idx < 4 * IDIM; idx += 256) {
    const int tt = idx / IDIM, oo = idx % IDIM;
    out_pred[((size_t)b * TDEC + t0 + tt) * IDIM + oo] =
        sc_l[tt][oo] - sc_lse[tt];
  }
}

extern "C" void kernel_launch(void* const* d_in, const int* in_sizes, int n_in,
                              void* d_out, int out_size, void* d_ws, size_t ws_size,
                              hipStream_t stream) {
  const float* enc_feat = (const float*)d_in[0];
  const float* gt       = (const float*)d_in[1];
  const float* W_ih     = (const float*)d_in[2];
  const float* W_hh     = (const float*)d_in[3];
  const float* b_ih     = (const float*)d_in[4];
  const float* b_hh     = (const float*)d_in[5];
  const float* W_enc    = (const float*)d_in[6];
  const float* W_dec    = (const float*)d_in[7];
  const float* b_attn   = (const float*)d_in[8];
  const float* v_attn   = (const float*)d_in[9];
  const float* W_out    = (const float*)d_in[10];
  const float* b_out    = (const float*)d_in[11];
  float* out_pred = (float*)d_out;
  float* out_attn = out_pred + (size_t)BB * TDEC * IDIM;

  char* ws = (char*)d_ws;
  size_t off = 0;
  u16* gi_x   = (u16*)(ws + off);   off += (size_t)BB * TDEC * G3 * 2;
  u16* encp   = (u16*)(ws + off);   off += (size_t)BB * TENC * ADIM * 2;
  u16* enc_bf = (u16*)(ws + off);   off += (size_t)BB * TENC * EDIM * 2;
  float* stash= (float*)(ws + off); off += (size_t)BB * TDEC * 512 * 4;
  // ---- zeroed region (one memset): tagged slot arrays (tags start at 0) ----
  char* zbase = ws + off;
  float2* XhS   = (float2*)(ws + off); off += (size_t)BB * GDIM * 8;
  float2* DaccS = (float2*)(ws + off); off += (size_t)BB * NSL * ADIM * 8;
  float2* XctxS = (float2*)(ws + off); off += (size_t)BB * NSL * XCST * 8;
  const size_t zbytes = (size_t)(ws + off - zbase);

  // dynamic LDS for k_decode: encp slice + transposed enc slice
  const int DYNB = (SLT * EPST + EDIM * ETST) * 2;  // 79424 B
  static bool s_attr = false;
  if (!s_attr) {
    (void)hipFuncSetAttribute(reinterpret_cast<const void*>(k_decode),
                              hipFuncAttributeMaxDynamicSharedMemorySize, DYNB);
    s_attr = true;
  }

  hipMemsetAsync(zbase, 0, zbytes, stream);

  hipLaunchKernelGGL(k_gix, dim3(BB * 50), dim3(256), 0, stream,
                     gt, W_ih, b_ih, gi_x);
  hipLaunchKernelGGL(k_encp, dim3(BB * 50), dim3(256), 0, stream,
                     enc_feat, W_enc, encp, enc_bf);
  hipLaunchKernelGGL(k_decode, dim3(BB * NSL), dim3(512), DYNB, stream,
                     W_ih, W_hh, b_hh, W_dec, b_attn, v_attn,
                     gi_x, encp, enc_bf, stash, XhS, DaccS, XctxS, out_attn);
  hipLaunchKernelGGL(k_pred, dim3(BB * 100), dim3(256), 0, stream,
                     stash, W_out, b_out, out_pred);
}